// Round 4
// baseline (164.497 us; speedup 1.0000x reference)
//
#include <hip/hip_runtime.h>
#include <hip/hip_bf16.h>

typedef __hip_bfloat16 bf16;
typedef unsigned short u16;
typedef unsigned int   u32;

#define B_    32
#define D_    512
#define HID_  256
#define NF_   8
#define CIN_  64
#define COUT_ 64
#define HW_   64
#define CONV_OUT_ELEMS (B_ * COUT_ * HW_ * HW_)   // 8388608
#define WBANK_ (NF_ * 36864)                       // weight elems

typedef __attribute__((ext_vector_type(8))) short  short8;   // 8 bf16 = 4 VGPRs (MFMA A/B frag)
typedef __attribute__((ext_vector_type(4))) float  floatx4;  // MFMA C/D frag

__device__ inline float b2f(bf16 v) { return __bfloat162float(v); }
__device__ inline bf16  f2b(float f) { return __float2bfloat16(f); }
__device__ inline u16 f2bu(float f) { union { bf16 h; u16 u; } c; c.h = __float2bfloat16(f); return c.u; }
__device__ inline float bu2f(u16 u) { union { u32 i; float f; } c; c.i = ((u32)u) << 16; return c.f; }

__device__ inline float ldf(const void* p, int i, int isbf) {
    return isbf ? __bfloat162float(((const bf16*)p)[i]) : ((const float*)p)[i];
}

// word is "bf16-sane" if low 16 bits decode to zero or normal-exponent bf16
__device__ inline int word_bf16_sane(u32 v) {
    u32 lo = v & 0xFFFFu;
    u32 ex = (lo >> 7) & 0xFFu;
    return (lo == 0u || (ex >= 64u && ex <= 191u)) ? 1 : 0;
}

// ---------------------------------------------------------------------------
// Kernel 1: routing MLP + softmax + agg bias.  grid=32 (one block per sample).
// Wave-parallel: fc1 = one hidden unit per wave-iteration, coalesced 16B/lane
// loads + shfl_xor reduction. Dtype sniff parallel across 224 threads.
// ---------------------------------------------------------------------------
__global__ __launch_bounds__(256) void routing_kernel(
    const void* __restrict__ x, const void* __restrict__ xin,
    const void* __restrict__ fc1_w, const void* __restrict__ fc1_b,
    const void* __restrict__ fc2_w, const void* __restrict__ fc2_b,
    const void* __restrict__ bias_p,
    float* __restrict__ ws_attn, float* __restrict__ ws_aggb,
    void* __restrict__ d_out)
{
    __shared__ float xs[D_];
    __shared__ float hs[HID_];
    __shared__ float at[NF_];
    __shared__ int   fl[8];
    const int b = blockIdx.x;
    const int t = threadIdx.x;
    const int w = t >> 6, l = t & 63;

    if (t < 8) fl[t] = 1;
    __syncthreads();
    // parallel dtype detection: 7 buffers x 32 sampled words
    if (t < 224) {
        const void* bufs[7]  = { x, fc1_w, fc1_b, fc2_w, fc2_b, bias_p, xin };
        const int   elems[7] = { B_ * D_, HID_ * D_, HID_, NF_ * HID_, NF_,
                                 NF_ * COUT_, B_ * CIN_ * HW_ * HW_ };
        const int g = t >> 5, k = t & 31;
        const int nw = elems[g] >> 1;
        const int n = nw < 32 ? nw : 32;
        if (k < n && nw >= 1) {
            const int step = nw / n;
            u32 v = ((const u32*)bufs[g])[k * step];
            if (!word_bf16_sane(v)) atomicAnd(&fl[g], 0);
        }
    }
    __syncthreads();
    const int xbf = fl[0], w1bf = fl[1], b1bf = fl[2], w2bf = fl[3];
    const int b2bf = fl[4], bpbf = fl[5], obf = fl[6];

    for (int i = t; i < D_; i += 256) xs[i] = ldf(x, b * D_ + i, xbf);
    __syncthreads();

    // fc1: wave w computes hids [w*64, w*64+64); lane l covers k = 8l..8l+7
    const float* xp = xs + l * 8;
#pragma unroll 2
    for (int hi = 0; hi < 64; ++hi) {
        const int h = w * 64 + hi;
        float p;
        if (w1bf) {
            uint4 u = *(const uint4*)((const bf16*)fc1_w + h * D_ + l * 8);
            p = bu2f((u16)(u.x & 0xFFFF)) * xp[0] + bu2f((u16)(u.x >> 16)) * xp[1]
              + bu2f((u16)(u.y & 0xFFFF)) * xp[2] + bu2f((u16)(u.y >> 16)) * xp[3]
              + bu2f((u16)(u.z & 0xFFFF)) * xp[4] + bu2f((u16)(u.z >> 16)) * xp[5]
              + bu2f((u16)(u.w & 0xFFFF)) * xp[6] + bu2f((u16)(u.w >> 16)) * xp[7];
        } else {
            const float* r = (const float*)fc1_w + h * D_ + l * 8;
            float4 a = *(const float4*)r, c = *(const float4*)(r + 4);
            p = a.x * xp[0] + a.y * xp[1] + a.z * xp[2] + a.w * xp[3]
              + c.x * xp[4] + c.y * xp[5] + c.z * xp[6] + c.w * xp[7];
        }
#pragma unroll
        for (int m = 32; m; m >>= 1) p += __shfl_xor(p, m);
        if (l == 0) {
            p += ldf(fc1_b, h, b1bf);
            hs[h] = p > 0.f ? p : 0.f;
        }
    }
    __syncthreads();

    // fc2: wave w computes logits 2w, 2w+1 (coalesced lane-parallel dot)
#pragma unroll
    for (int ff = 0; ff < 2; ++ff) {
        const int f = w * 2 + ff;
        float p = 0.f;
#pragma unroll
        for (int j = 0; j < 4; ++j)
            p += hs[j * 64 + l] * ldf(fc2_w, f * HID_ + j * 64 + l, w2bf);
#pragma unroll
        for (int m = 32; m; m >>= 1) p += __shfl_xor(p, m);
        if (l == 0) at[f] = (p + ldf(fc2_b, f, b2bf)) * (1.0f / 30.0f);
    }
    __syncthreads();

    if (t == 0) {
        float m = at[0];
#pragma unroll
        for (int f = 1; f < NF_; ++f) m = fmaxf(m, at[f]);
        float e[NF_], ssum = 0.f;
#pragma unroll
        for (int f = 0; f < NF_; ++f) { e[f] = __expf(at[f] - m); ssum += e[f]; }
        float inv = 1.0f / ssum;
#pragma unroll
        for (int f = 0; f < NF_; ++f) at[f] = e[f] * inv;
    }
    __syncthreads();
    if (t < NF_) {
        ws_attn[b * NF_ + t] = at[t];
        if (obf) ((bf16*)d_out)[CONV_OUT_ELEMS + b * NF_ + t] = f2b(at[t]);
        else    ((float*)d_out)[CONV_OUT_ELEMS + b * NF_ + t] = at[t];
    }
    if (t < COUT_) {
        float s = 0.f;
#pragma unroll
        for (int f = 0; f < NF_; ++f) s += at[f] * ldf(bias_p, f * COUT_ + t, bpbf);
        ws_aggb[b * COUT_ + t] = s;
    }
}

// ---------------------------------------------------------------------------
// Kernel 2: aggregate kernel bank -> bf16 in MFMA layout [b][tap][o][ci].
// grid = 32 samples * 16 o-quads = 512 blocks, 256 threads.
// ---------------------------------------------------------------------------
__global__ __launch_bounds__(256) void agg_kernel(
    const void* __restrict__ weight,   // [8][64][64][3][3]
    const float* __restrict__ ws_attn, // [32][8]
    u16* __restrict__ aggw)            // [32][9][64][64] bf16
{
    __shared__ float lds[2304];        // [o_l(4)][ci(64)][tap(9)]
    __shared__ float s_at[NF_];
    __shared__ int   s_wbf;
    const int t  = threadIdx.x;
    const int b  = blockIdx.x >> 4;
    const int o0 = (blockIdx.x & 15) * 4;

    if (t == 0) s_wbf = 1;
    if (t < NF_) s_at[t] = ws_attn[b * NF_ + t];
    __syncthreads();
    if (t < 32) {
        const int nw = WBANK_ >> 1, step = nw / 32;
        u32 v = ((const u32*)weight)[t * step];
        if (!word_bf16_sane(v)) atomicAnd(&s_wbf, 0);
    }
    __syncthreads();
    const int wbf = s_wbf;

#pragma unroll
    for (int j = 0; j < 9; ++j) {
        const int flat = t + 256 * j;              // < 2304
        const int o_l = flat / 576, rr = flat - o_l * 576;  // rr = ci*9+tap
        const int gbase = (o0 + o_l) * 576 + rr;
        float s = 0.f;
        if (wbf) {
#pragma unroll
            for (int f = 0; f < NF_; ++f) s += s_at[f] * b2f(((const bf16*)weight)[f * 36864 + gbase]);
        } else {
#pragma unroll
            for (int f = 0; f < NF_; ++f) s += s_at[f] * ((const float*)weight)[f * 36864 + gbase];
        }
        lds[flat] = s;
    }
    __syncthreads();
#pragma unroll
    for (int j = 0; j < 9; ++j) {
        const int e = t + 256 * j;                 // tap(9) x o_l(4) x ci(64)
        const int tap = e >> 8, o_l = (e >> 6) & 3, ci = e & 63;
        aggw[b * 36864 + tap * 4096 + (o0 + o_l) * 64 + ci] = f2bu(lds[o_l * 576 + ci * 9 + tap]);
    }
}

// ---------------------------------------------------------------------------
// Kernel 3: MFMA implicit-GEMM conv (per tap: C[o][x] += W[o][ci] * X[ci][x']).
// Block = (sample, 4-row chunk); 4 waves; wave = 1 output row x 64 couts.
// in_s layout: ((r*4+cib)*66 + col)*8 + cj   (col = gx+1, ci = cib*8+cj)
// w_s  layout: ((tap*4+cib)*64 + o )*8 + cj
// ---------------------------------------------------------------------------
__global__ __launch_bounds__(256, 2) void conv_mfma(
    const void* __restrict__ xin,     // [32][64][64][64]
    const u16*  __restrict__ aggw,    // [32][9][64][64] bf16
    const float* __restrict__ aggb,   // [32][64]
    void* __restrict__ out)
{
    __shared__ __align__(16) u16 smem[31104];   // 62208 B: in_s(12672) + w_s(18432); reused as out_s
    __shared__ float bias_s[COUT_];
    __shared__ int s_ok;
    u16* in_s = smem;
    u16* w_s  = smem + 12672;

    const int t    = threadIdx.x;
    const int bz   = blockIdx.x;
    const int b    = bz >> 4;
    const int y0   = (bz & 15) * 4;
    const int wv   = t >> 6;
    const int lane = t & 63, l15 = lane & 15, q = lane >> 4;

    if (t == 0) s_ok = 1;
    __syncthreads();
    if (t < 32) {
        u32 w = ((const u32*)xin)[t * 131072];
        if (!word_bf16_sane(w)) atomicAnd(&s_ok, 0);
    }
    if (t < COUT_) bias_s[t] = aggb[b * COUT_ + t];
    __syncthreads();
    const int inbf = s_ok;

    floatx4 acc[4][4];
#pragma unroll
    for (int mt = 0; mt < 4; ++mt)
#pragma unroll
        for (int nt = 0; nt < 4; ++nt) acc[mt][nt] = (floatx4)0.f;

    for (int ph = 0; ph < 2; ++ph) {
        const int ci0 = ph * 32;
        __syncthreads();   // protect previous phase's LDS reads
        // ---- stage weights: 9 taps x 4 cib x 64 o, 16B per item
#pragma unroll
        for (int j = 0; j < 9; ++j) {
            const int item = t + 256 * j;
            const int o = item & 63, cib = (item >> 6) & 3, tap = item >> 8;
            uint4 v = *(const uint4*)(aggw + b * 36864 + tap * 4096 + o * 64 + ci0 + cib * 8);
            *(uint4*)&w_s[((tap * 4 + cib) * 64 + o) * 8] = v;
        }
        // ---- stage input (transposed to pixel-major x ci-contiguous)
#pragma unroll
        for (int j = 0; j < 3; ++j) {
            const int item = t + 256 * j;          // 768 items
            const int cp = item & 15, z = item >> 4;
            const int r = z % 6, ch = z / 6;
            const int gy = y0 - 1 + r, gx0 = ch * 8;
            const int ci = ci0 + cp * 2;
            union { uint4 v; u16 s[8]; } a0, a1;
            if (gy >= 0 && gy < HW_) {
                const int gi = ((b * CIN_ + ci) * HW_ + gy) * HW_ + gx0;
                if (inbf) {
                    a0.v = *(const uint4*)((const bf16*)xin + gi);
                    a1.v = *(const uint4*)((const bf16*)xin + gi + HW_ * HW_);
                } else {
                    const float* p0 = (const float*)xin + gi;
                    const float* p1 = p0 + HW_ * HW_;
                    float4 f00 = *(const float4*)p0, f01 = *(const float4*)(p0 + 4);
                    float4 f10 = *(const float4*)p1, f11 = *(const float4*)(p1 + 4);
                    a0.s[0]=f2bu(f00.x); a0.s[1]=f2bu(f00.y); a0.s[2]=f2bu(f00.z); a0.s[3]=f2bu(f00.w);
                    a0.s[4]=f2bu(f01.x); a0.s[5]=f2bu(f01.y); a0.s[6]=f2bu(f01.z); a0.s[7]=f2bu(f01.w);
                    a1.s[0]=f2bu(f10.x); a1.s[1]=f2bu(f10.y); a1.s[2]=f2bu(f10.z); a1.s[3]=f2bu(f10.w);
                    a1.s[4]=f2bu(f11.x); a1.s[5]=f2bu(f11.y); a1.s[6]=f2bu(f11.z); a1.s[7]=f2bu(f11.w);
                }
            } else {
                a0.v = make_uint4(0,0,0,0); a1.v = make_uint4(0,0,0,0);
            }
            const int cib = cp >> 2, p = cp & 3;
            u32* dst = (u32*)in_s;
#pragma unroll
            for (int k = 0; k < 8; ++k) {
                const int col = 1 + gx0 + k;
                dst[((r * 4 + cib) * 66 + col) * 4 + p] = (u32)a0.s[k] | ((u32)a1.s[k] << 16);
            }
        }
        // zero halo columns (gx = -1 and 64)
        if (t < 192) {
            const int cp = t & 15, z = t >> 4;
            const int r = z % 6, col = (z / 6) ? 65 : 0;
            ((u32*)in_s)[((r * 4 + (cp >> 2)) * 66 + col) * 4 + (cp & 3)] = 0u;
        }
        __syncthreads();
        // ---- 9 taps x 16 MFMA tiles
#pragma unroll
        for (int tap = 0; tap < 9; ++tap) {
            const int kh = tap / 3, kw = tap % 3;
            short8 af[4], bfr[4];
#pragma unroll
            for (int mt = 0; mt < 4; ++mt)
                af[mt] = *(const short8*)&w_s[((tap * 4 + q) * 64 + mt * 16 + l15) * 8];
#pragma unroll
            for (int nt = 0; nt < 4; ++nt)
                bfr[nt] = *(const short8*)&in_s[(((wv + kh) * 4 + q) * 66 + nt * 16 + l15 + kw) * 8];
#pragma unroll
            for (int mt = 0; mt < 4; ++mt)
#pragma unroll
                for (int nt = 0; nt < 4; ++nt)
                    acc[mt][nt] = __builtin_amdgcn_mfma_f32_16x16x32_bf16(af[mt], bfr[nt], acc[mt][nt], 0, 0, 0);
        }
    }

    __syncthreads();   // all MFMA LDS reads done; reuse smem as out staging
    u16* out_s = smem; // [wv][o][68]
#pragma unroll
    for (int mt = 0; mt < 4; ++mt) {
        floatx4 bb = *(const floatx4*)&bias_s[mt * 16 + q * 4];
#pragma unroll
        for (int nt = 0; nt < 4; ++nt) {
#pragma unroll
            for (int rg = 0; rg < 4; ++rg) {
                const float v = acc[mt][nt][rg] + bb[rg];
                out_s[(wv * 64 + (mt * 16 + q * 4 + rg)) * 68 + nt * 16 + l15] = f2bu(v);
            }
        }
    }
    __syncthreads();
    const int outbf = inbf;
#pragma unroll
    for (int j = 0; j < 16; ++j) {
        const int c = t + 256 * j;                 // 4096 chunks of 4 elems
        const int x0 = (c & 15) * 4, o = (c >> 4) & 63, w2 = c >> 10;
        const u16* src = &out_s[(w2 * 64 + o) * 68 + x0];
        const u16 h0 = src[0], h1 = src[1], h2 = src[2], h3 = src[3];
        const int gidx = ((b * COUT_ + o) * HW_ + (y0 + w2)) * HW_ + x0;
        if (outbf) {
            uint2 pk; pk.x = (u32)h0 | ((u32)h1 << 16); pk.y = (u32)h2 | ((u32)h3 << 16);
            *(uint2*)((u16*)out + gidx) = pk;
        } else {
            float4 f; f.x = bu2f(h0); f.y = bu2f(h1); f.z = bu2f(h2); f.w = bu2f(h3);
            *(float4*)((float*)out + gidx) = f;
        }
    }
}

// ---------------------------------------------------------------------------
extern "C" void kernel_launch(void* const* d_in, const int* in_sizes, int n_in,
                              void* d_out, int out_size, void* d_ws, size_t ws_size,
                              hipStream_t stream) {
    const void* x      = d_in[0];
    const void* xin    = d_in[1];
    const void* fc1_w  = d_in[2];
    const void* fc1_b  = d_in[3];
    const void* fc2_w  = d_in[4];
    const void* fc2_b  = d_in[5];
    const void* weight = d_in[6];
    const void* bias_p = d_in[7];

    float* ws      = (float*)d_ws;
    float* ws_attn = ws;                    // 256 floats
    float* ws_aggb = ws + 256;              // 2048 floats
    u16*   ws_aggw = (u16*)(ws + 2304);     // 32*9*64*64 bf16 = 2.36 MB

    routing_kernel<<<dim3(B_), dim3(256), 0, stream>>>(
        x, xin, fc1_w, fc1_b, fc2_w, fc2_b, bias_p, ws_attn, ws_aggb, d_out);

    agg_kernel<<<dim3(B_ * 16), dim3(256), 0, stream>>>(weight, ws_attn, ws_aggw);

    conv_mfma<<<dim3(B_ * 16), dim3(256), 0, stream>>>(xin, ws_aggw, ws_aggb, d_out);
}

// Round 6
// 130.348 us; speedup vs baseline: 1.2620x; 1.2620x over previous
//
#include <hip/hip_runtime.h>
#include <hip/hip_bf16.h>

typedef __hip_bfloat16 bf16;
typedef unsigned short u16;
typedef unsigned int   u32;

#define B_    32
#define D_    512
#define HID_  256
#define NF_   8
#define CIN_  64
#define COUT_ 64
#define HW_   64
#define CONV_OUT_ELEMS (B_ * COUT_ * HW_ * HW_)   // 8388608
#define WBANK_ (NF_ * 36864)                       // weight elems

typedef __attribute__((ext_vector_type(8))) short  short8;   // 8 bf16 = 4 VGPRs (MFMA A/B frag)
typedef __attribute__((ext_vector_type(4))) float  floatx4;  // MFMA C/D frag

__device__ inline float b2f(bf16 v) { return __bfloat162float(v); }
__device__ inline bf16  f2b(float f) { return __float2bfloat16(f); }
__device__ inline u16 f2bu(float f) { union { bf16 h; u16 u; } c; c.h = __float2bfloat16(f); return c.u; }
__device__ inline float bu2f(u16 u) { union { u32 i; float f; } c; c.i = ((u32)u) << 16; return c.f; }

__device__ inline float ldf(const void* p, int i, int isbf) {
    return isbf ? __bfloat162float(((const bf16*)p)[i]) : ((const float*)p)[i];
}

// word is "bf16-sane" if low 16 bits decode to zero or normal-exponent bf16
__device__ inline int word_bf16_sane(u32 v) {
    u32 lo = v & 0xFFFFu;
    u32 ex = (lo >> 7) & 0xFFu;
    return (lo == 0u || (ex >= 64u && ex <= 191u)) ? 1 : 0;
}

// ---------------------------------------------------------------------------
// Kernel 1a: fc1.  grid = 256 (one hidden unit per block), 256 threads.
// Thread (b = t>>3, seg = t&7) covers k in [seg*64, seg*64+64): ALL 64 elems
// (16 float4 / 8 uint4 loads) issued up-front, 3-step shfl reduction over seg.
// ---------------------------------------------------------------------------
__global__ __launch_bounds__(256) void fc1_kernel(
    const void* __restrict__ x,      // [32,512]
    const void* __restrict__ fc1_w,  // [256,512]
    const void* __restrict__ fc1_b,  // [256]
    float* __restrict__ ws_hs)       // [32,256]
{
    const int h = blockIdx.x;
    const int t = threadIdx.x;
    const int b = t >> 3, seg = t & 7;
    __shared__ int fl[3];
    if (t < 3) fl[t] = 1;
    __syncthreads();
    if (t < 96) {
        const int g = t >> 5, k = t & 31;
        const void* buf = (g == 0) ? x : (g == 1) ? fc1_w : fc1_b;
        const int elems = (g == 0) ? B_ * D_ : (g == 1) ? HID_ * D_ : HID_;
        const int nw = elems >> 1;
        const int n = nw < 32 ? nw : 32;
        if (k < n && nw >= 1) {
            u32 v = ((const u32*)buf)[k * (nw / n)];
            if (!word_bf16_sane(v)) atomicAnd(&fl[g], 0);
        }
    }
    __syncthreads();
    const int xbf = fl[0], wbf = fl[1], b1bf = fl[2];

    const int xoff = b * D_ + seg * 64;
    const int woff = h * D_ + seg * 64;
    float p = 0.f;
    if (!xbf && !wbf) {
        float4 xr[16], wr[16];                      // 16 x float4 = 64 floats
        const float4* xp = (const float4*)((const float*)x + xoff);
        const float4* wp = (const float4*)((const float*)fc1_w + woff);
#pragma unroll
        for (int c = 0; c < 16; ++c) xr[c] = xp[c];
#pragma unroll
        for (int c = 0; c < 16; ++c) wr[c] = wp[c];
#pragma unroll
        for (int c = 0; c < 16; ++c)
            p += xr[c].x * wr[c].x + xr[c].y * wr[c].y + xr[c].z * wr[c].z + xr[c].w * wr[c].w;
    } else if (xbf && wbf) {
        uint4 xr[8], wr[8];                         // 8 x uint4 = 64 bf16
        const uint4* xp = (const uint4*)((const bf16*)x + xoff);
        const uint4* wp = (const uint4*)((const bf16*)fc1_w + woff);
#pragma unroll
        for (int c = 0; c < 8; ++c) xr[c] = xp[c];
#pragma unroll
        for (int c = 0; c < 8; ++c) wr[c] = wp[c];
#pragma unroll
        for (int c = 0; c < 8; ++c) {
            const u32 xw[4] = { xr[c].x, xr[c].y, xr[c].z, xr[c].w };
            const u32 ww[4] = { wr[c].x, wr[c].y, wr[c].z, wr[c].w };
#pragma unroll
            for (int q2 = 0; q2 < 4; ++q2)
                p += bu2f((u16)(xw[q2] & 0xFFFF)) * bu2f((u16)(ww[q2] & 0xFFFF))
                   + bu2f((u16)(xw[q2] >> 16))    * bu2f((u16)(ww[q2] >> 16));
        }
    } else {
        for (int c = 0; c < 64; ++c) p += ldf(x, xoff + c, xbf) * ldf(fc1_w, woff + c, wbf);
    }
    p += __shfl_xor(p, 1);
    p += __shfl_xor(p, 2);
    p += __shfl_xor(p, 4);
    if (seg == 0) {
        p += ldf(fc1_b, h, b1bf);
        ws_hs[b * HID_ + h] = p > 0.f ? p : 0.f;
    }
}

// ---------------------------------------------------------------------------
// Kernel 1b: fc2 + softmax + attn outputs + aggregated bias.  grid = 32.
// ---------------------------------------------------------------------------
__global__ __launch_bounds__(256) void fc2_kernel(
    const void* __restrict__ fc2_w,  // [8,256]
    const void* __restrict__ fc2_b,  // [8]
    const void* __restrict__ bias_p, // [8,64]
    const void* __restrict__ xin,    // output-dtype proxy
    const float* __restrict__ ws_hs, // [32,256]
    float* __restrict__ ws_attn, float* __restrict__ ws_aggb,
    void* __restrict__ d_out)
{
    __shared__ float hs[HID_];
    __shared__ float at[NF_];
    __shared__ int fl[4];
    const int b = blockIdx.x, t = threadIdx.x;
    if (t < 4) fl[t] = 1;
    hs[t] = ws_hs[b * HID_ + t];
    __syncthreads();
    if (t < 128) {
        const int g = t >> 5, k = t & 31;
        const void* buf = (g == 0) ? fc2_w : (g == 1) ? fc2_b : (g == 2) ? bias_p : xin;
        const int elems = (g == 0) ? NF_ * HID_ : (g == 1) ? NF_ : (g == 2) ? NF_ * COUT_
                                                : B_ * CIN_ * HW_ * HW_;
        const int nw = elems >> 1;
        const int n = nw < 32 ? nw : 32;
        if (k < n && nw >= 1) {
            u32 v = ((const u32*)buf)[k * (nw / n)];
            if (!word_bf16_sane(v)) atomicAnd(&fl[g], 0);
        }
    }
    __syncthreads();
    const int w2bf = fl[0], b2bf = fl[1], bpbf = fl[2], obf = fl[3];

    // logits: f = t>>5 (8 logit-groups x 32 lanes), lane j covers k = j*8..j*8+8
    const int f = t >> 5, j = t & 31;
    const float* hp = hs + j * 8;
    float p;
    if (w2bf) {
        uint4 u = *(const uint4*)((const bf16*)fc2_w + f * HID_ + j * 8);
        p = bu2f((u16)(u.x & 0xFFFF)) * hp[0] + bu2f((u16)(u.x >> 16)) * hp[1]
          + bu2f((u16)(u.y & 0xFFFF)) * hp[2] + bu2f((u16)(u.y >> 16)) * hp[3]
          + bu2f((u16)(u.z & 0xFFFF)) * hp[4] + bu2f((u16)(u.z >> 16)) * hp[5]
          + bu2f((u16)(u.w & 0xFFFF)) * hp[6] + bu2f((u16)(u.w >> 16)) * hp[7];
    } else {
        const float* r = (const float*)fc2_w + f * HID_ + j * 8;
        float4 a = *(const float4*)r, c = *(const float4*)(r + 4);
        p = a.x * hp[0] + a.y * hp[1] + a.z * hp[2] + a.w * hp[3]
          + c.x * hp[4] + c.y * hp[5] + c.z * hp[6] + c.w * hp[7];
    }
#pragma unroll
    for (int m = 16; m; m >>= 1) p += __shfl_xor(p, m);
    if (j == 0) at[f] = (p + ldf(fc2_b, f, b2bf)) * (1.0f / 30.0f);
    __syncthreads();

    if (t == 0) {
        float m = at[0];
#pragma unroll
        for (int ff = 1; ff < NF_; ++ff) m = fmaxf(m, at[ff]);
        float e[NF_], ssum = 0.f;
#pragma unroll
        for (int ff = 0; ff < NF_; ++ff) { e[ff] = __expf(at[ff] - m); ssum += e[ff]; }
        float inv = 1.0f / ssum;
#pragma unroll
        for (int ff = 0; ff < NF_; ++ff) at[ff] = e[ff] * inv;
    }
    __syncthreads();
    if (t < NF_) {
        ws_attn[b * NF_ + t] = at[t];
        if (obf) ((bf16*)d_out)[CONV_OUT_ELEMS + b * NF_ + t] = f2b(at[t]);
        else    ((float*)d_out)[CONV_OUT_ELEMS + b * NF_ + t] = at[t];
    }
    if (t < COUT_) {
        float s = 0.f;
#pragma unroll
        for (int ff = 0; ff < NF_; ++ff) s += at[ff] * ldf(bias_p, ff * COUT_ + t, bpbf);
        ws_aggb[b * COUT_ + t] = s;
    }
}

// ---------------------------------------------------------------------------
// Kernel 2: aggregate kernel bank -> bf16 in MFMA layout [b][tap][o][ci].
// grid = 32 samples * 16 o-quads = 512 blocks, 256 threads.
// ---------------------------------------------------------------------------
__global__ __launch_bounds__(256) void agg_kernel(
    const void* __restrict__ weight,   // [8][64][64][3][3]
    const float* __restrict__ ws_attn, // [32][8]
    u16* __restrict__ aggw)            // [32][9][64][64] bf16
{
    __shared__ float lds[2304];        // [o_l(4)][ci(64)][tap(9)]
    __shared__ float s_at[NF_];
    __shared__ int   s_wbf;
    const int t  = threadIdx.x;
    const int b  = blockIdx.x >> 4;
    const int o0 = (blockIdx.x & 15) * 4;

    if (t == 0) s_wbf = 1;
    if (t < NF_) s_at[t] = ws_attn[b * NF_ + t];
    __syncthreads();
    if (t < 32) {
        const int nw = WBANK_ >> 1, step = nw / 32;
        u32 v = ((const u32*)weight)[t * step];
        if (!word_bf16_sane(v)) atomicAnd(&s_wbf, 0);
    }
    __syncthreads();
    const int wbf = s_wbf;

#pragma unroll
    for (int j = 0; j < 9; ++j) {
        const int flat = t + 256 * j;              // < 2304
        const int o_l = flat / 576, rr = flat - o_l * 576;  // rr = ci*9+tap
        const int gbase = (o0 + o_l) * 576 + rr;
        float s = 0.f;
        if (wbf) {
#pragma unroll
            for (int f = 0; f < NF_; ++f) s += s_at[f] * b2f(((const bf16*)weight)[f * 36864 + gbase]);
        } else {
#pragma unroll
            for (int f = 0; f < NF_; ++f) s += s_at[f] * ((const float*)weight)[f * 36864 + gbase];
        }
        lds[flat] = s;
    }
    __syncthreads();
#pragma unroll
    for (int j = 0; j < 9; ++j) {
        const int e = t + 256 * j;                 // tap(9) x o_l(4) x ci(64)
        const int tap = e >> 8, o_l = (e >> 6) & 3, ci = e & 63;
        aggw[b * 36864 + tap * 4096 + (o0 + o_l) * 64 + ci] = f2bu(lds[o_l * 576 + ci * 9 + tap]);
    }
}

// ---------------------------------------------------------------------------
// Kernel 3: MFMA implicit-GEMM conv (per tap: C[o][x] += W[o][ci] * X[ci][x']).
// Block = (sample, 4-row chunk); 4 waves; wave = 1 output row x 64 couts.
// in_s layout: ((r*4+cib)*66 + col)*8 + cj   (col = gx+1, ci = cib*8+cj)
// w_s  layout: ((tap*4+cib)*64 + o )*8 + cj
// ---------------------------------------------------------------------------
__global__ __launch_bounds__(256, 2) void conv_mfma(
    const void* __restrict__ xin,     // [32][64][64][64]
    const u16*  __restrict__ aggw,    // [32][9][64][64] bf16
    const float* __restrict__ aggb,   // [32][64]
    void* __restrict__ out)
{
    __shared__ __align__(16) u16 smem[31104];   // 62208 B: in_s(12672) + w_s(18432); reused as out_s
    __shared__ float bias_s[COUT_];
    __shared__ int s_ok;
    u16* in_s = smem;
    u16* w_s  = smem + 12672;

    const int t    = threadIdx.x;
    const int bz   = blockIdx.x;
    const int b    = bz >> 4;
    const int y0   = (bz & 15) * 4;
    const int wv   = t >> 6;
    const int lane = t & 63, l15 = lane & 15, q = lane >> 4;

    if (t == 0) s_ok = 1;
    __syncthreads();
    if (t < 32) {
        u32 w = ((const u32*)xin)[t * 131072];
        if (!word_bf16_sane(w)) atomicAnd(&s_ok, 0);
    }
    if (t < COUT_) bias_s[t] = aggb[b * COUT_ + t];
    __syncthreads();
    const int inbf = s_ok;

    floatx4 acc[4][4];
#pragma unroll
    for (int mt = 0; mt < 4; ++mt)
#pragma unroll
        for (int nt = 0; nt < 4; ++nt) acc[mt][nt] = (floatx4)0.f;

    for (int ph = 0; ph < 2; ++ph) {
        const int ci0 = ph * 32;
        __syncthreads();   // protect previous phase's LDS reads
        // ---- stage weights: 9 taps x 4 cib x 64 o, 16B per item
#pragma unroll
        for (int j = 0; j < 9; ++j) {
            const int item = t + 256 * j;
            const int o = item & 63, cib = (item >> 6) & 3, tap = item >> 8;
            uint4 v = *(const uint4*)(aggw + b * 36864 + tap * 4096 + o * 64 + ci0 + cib * 8);
            *(uint4*)&w_s[((tap * 4 + cib) * 64 + o) * 8] = v;
        }
        // ---- stage input (transposed to pixel-major x ci-contiguous)
#pragma unroll
        for (int j = 0; j < 3; ++j) {
            const int item = t + 256 * j;          // 768 items
            const int cp = item & 15, z = item >> 4;
            const int r = z % 6, ch = z / 6;
            const int gy = y0 - 1 + r, gx0 = ch * 8;
            const int ci = ci0 + cp * 2;
            union { uint4 v; u16 s[8]; } a0, a1;
            if (gy >= 0 && gy < HW_) {
                const int gi = ((b * CIN_ + ci) * HW_ + gy) * HW_ + gx0;
                if (inbf) {
                    a0.v = *(const uint4*)((const bf16*)xin + gi);
                    a1.v = *(const uint4*)((const bf16*)xin + gi + HW_ * HW_);
                } else {
                    const float* p0 = (const float*)xin + gi;
                    const float* p1 = p0 + HW_ * HW_;
                    float4 f00 = *(const float4*)p0, f01 = *(const float4*)(p0 + 4);
                    float4 f10 = *(const float4*)p1, f11 = *(const float4*)(p1 + 4);
                    a0.s[0]=f2bu(f00.x); a0.s[1]=f2bu(f00.y); a0.s[2]=f2bu(f00.z); a0.s[3]=f2bu(f00.w);
                    a0.s[4]=f2bu(f01.x); a0.s[5]=f2bu(f01.y); a0.s[6]=f2bu(f01.z); a0.s[7]=f2bu(f01.w);
                    a1.s[0]=f2bu(f10.x); a1.s[1]=f2bu(f10.y); a1.s[2]=f2bu(f10.z); a1.s[3]=f2bu(f10.w);
                    a1.s[4]=f2bu(f11.x); a1.s[5]=f2bu(f11.y); a1.s[6]=f2bu(f11.z); a1.s[7]=f2bu(f11.w);
                }
            } else {
                a0.v = make_uint4(0,0,0,0); a1.v = make_uint4(0,0,0,0);
            }
            const int cib = cp >> 2, p = cp & 3;
            u32* dst = (u32*)in_s;
#pragma unroll
            for (int k = 0; k < 8; ++k) {
                const int col = 1 + gx0 + k;
                dst[((r * 4 + cib) * 66 + col) * 4 + p] = (u32)a0.s[k] | ((u32)a1.s[k] << 16);
            }
        }
        // zero halo columns (gx = -1 and 64)
        if (t < 192) {
            const int cp = t & 15, z = t >> 4;
            const int r = z % 6, col = (z / 6) ? 65 : 0;
            ((u32*)in_s)[((r * 4 + (cp >> 2)) * 66 + col) * 4 + (cp & 3)] = 0u;
        }
        __syncthreads();
        // ---- 9 taps x 16 MFMA tiles
#pragma unroll
        for (int tap = 0; tap < 9; ++tap) {
            const int kh = tap / 3, kw = tap % 3;
            short8 af[4], bfr[4];
#pragma unroll
            for (int mt = 0; mt < 4; ++mt)
                af[mt] = *(const short8*)&w_s[((tap * 4 + q) * 64 + mt * 16 + l15) * 8];
#pragma unroll
            for (int nt = 0; nt < 4; ++nt)
                bfr[nt] = *(const short8*)&in_s[(((wv + kh) * 4 + q) * 66 + nt * 16 + l15 + kw) * 8];
#pragma unroll
            for (int mt = 0; mt < 4; ++mt)
#pragma unroll
                for (int nt = 0; nt < 4; ++nt)
                    acc[mt][nt] = __builtin_amdgcn_mfma_f32_16x16x32_bf16(af[mt], bfr[nt], acc[mt][nt], 0, 0, 0);
        }
    }

    __syncthreads();   // all MFMA LDS reads done; reuse smem as out staging
    u16* out_s = smem; // [wv][o][68]
#pragma unroll
    for (int mt = 0; mt < 4; ++mt) {
        floatx4 bb = *(const floatx4*)&bias_s[mt * 16 + q * 4];
#pragma unroll
        for (int nt = 0; nt < 4; ++nt) {
#pragma unroll
            for (int rg = 0; rg < 4; ++rg) {
                const float v = acc[mt][nt][rg] + bb[rg];
                out_s[(wv * 64 + (mt * 16 + q * 4 + rg)) * 68 + nt * 16 + l15] = f2bu(v);
            }
        }
    }
    __syncthreads();
    const int outbf = inbf;
#pragma unroll
    for (int j = 0; j < 16; ++j) {
        const int c = t + 256 * j;                 // 4096 chunks of 4 elems
        const int x0 = (c & 15) * 4, o = (c >> 4) & 63, w2 = c >> 10;
        const u16* src = &out_s[(w2 * 64 + o) * 68 + x0];
        const u16 h0 = src[0], h1 = src[1], h2 = src[2], h3 = src[3];
        const int gidx = ((b * COUT_ + o) * HW_ + (y0 + w2)) * HW_ + x0;
        if (outbf) {
            uint2 pk; pk.x = (u32)h0 | ((u32)h1 << 16); pk.y = (u32)h2 | ((u32)h3 << 16);
            *(uint2*)((u16*)out + gidx) = pk;
        } else {
            float4 f; f.x = bu2f(h0); f.y = bu2f(h1); f.z = bu2f(h2); f.w = bu2f(h3);
            *(float4*)((float*)out + gidx) = f;
        }
    }
}

// ---------------------------------------------------------------------------
extern "C" void kernel_launch(void* const* d_in, const int* in_sizes, int n_in,
                              void* d_out, int out_size, void* d_ws, size_t ws_size,
                              hipStream_t stream) {
    const void* x      = d_in[0];
    const void* xin    = d_in[1];
    const void* fc1_w  = d_in[2];
    const void* fc1_b  = d_in[3];
    const void* fc2_w  = d_in[4];
    const void* fc2_b  = d_in[5];
    const void* weight = d_in[6];
    const void* bias_p = d_in[7];

    float* ws      = (float*)d_ws;
    float* ws_attn = ws;                    // 256 floats
    float* ws_aggb = ws + 256;              // 2048 floats
    float* ws_hs   = ws + 2304;             // 8192 floats [32][256]
    u16*   ws_aggw = (u16*)(ws + 10496);    // 32*9*64*64 bf16 = 2.36 MB

    fc1_kernel<<<dim3(HID_), dim3(256), 0, stream>>>(x, fc1_w, fc1_b, ws_hs);

    fc2_kernel<<<dim3(B_), dim3(256), 0, stream>>>(
        fc2_w, fc2_b, bias_p, xin, ws_hs, ws_attn, ws_aggb, d_out);

    agg_kernel<<<dim3(B_ * 16), dim3(256), 0, stream>>>(weight, ws_attn, ws_aggw);

    conv_mfma<<<dim3(B_ * 16), dim3(256), 0, stream>>>(xin, ws_aggw, ws_aggb, d_out);
}